// Round 11
// baseline (102.627 us; speedup 1.0000x reference)
//
#include <hip/hip_runtime.h>
#include <cstdint>

typedef _Float16 f16x8 __attribute__((ext_vector_type(8)));
typedef _Float16 f16x4 __attribute__((ext_vector_type(4)));
typedef float    f32x4 __attribute__((ext_vector_type(4)));

static constexpr int TB = 2;
static constexpr int TT = 2048;
static constexpr int TE = 768;
static constexpr int TH = 12;
static constexpr int TD = 64;
static constexpr int TM = TB * TT;      // 4096 rows (B*T)
static constexpr int TK = TE;           // 768 (K for both GEMMs)
static constexpr int NQKV = 3 * TE;     // 2304
static constexpr int NUNITS = 24 * 32;  // attn work units (head x 64-row qtile)

#define SCALE_LOG2E 0.18033688011112042f  /* (1/sqrt(64)) * log2(e) */

// async global->LDS, 16B per lane. LDS dest is wave-uniform base + lane*16.
__device__ __forceinline__ void gload16(const void* g, void* lds) {
  __builtin_amdgcn_global_load_lds(
      (__attribute__((address_space(1))) void*)(uintptr_t)g,
      (__attribute__((address_space(3))) void*)(uint32_t)(uintptr_t)lds, 16, 0, 0);
}

// ---------------------------------------------------------------------------
// f32 -> f16 convert. x -> row-major f16. w_qkv / w_final -> FRAGMENT-NATIVE
// Wf layout: f16 idx(n,k) = ((n>>4)*24 + (k>>5))*512 + ((k>>3)&3)*128
//                           + (n&15)*8 + (k&7)
// ---------------------------------------------------------------------------
__global__ void cvt3(const float* __restrict__ x, const float* __restrict__ wq,
                     const float* __restrict__ wf, _Float16* __restrict__ xh,
                     _Float16* __restrict__ wqh, _Float16* __restrict__ wfh) {
  const int NX = TM * TK / 4, NW = NQKV * TK / 4;
  int i = blockIdx.x * 256 + threadIdx.x;
  if (i < NX) {
    float4 v = ((const float4*)x)[i];
    f16x4 o = {(_Float16)v.x, (_Float16)v.y, (_Float16)v.z, (_Float16)v.w};
    *(f16x4*)&xh[(size_t)i * 4] = o;
  } else {
    const float4* src; _Float16* dst; int j;
    if (i < NX + NW) { src = (const float4*)wq; dst = wqh; j = i - NX; }
    else             { src = (const float4*)wf; dst = wfh; j = i - NX - NW; }
    float4 v = src[j];
    f16x4 o = {(_Float16)v.x, (_Float16)v.y, (_Float16)v.z, (_Float16)v.w};
    const int flat = j * 4;
    const int n = flat / TK, k = flat % TK;
    const size_t idx = ((size_t)(n >> 4) * 24 + (k >> 5)) * 512 +
                       ((k >> 3) & 3) * 128 + (n & 15) * 8 + (k & 7);
    *(f16x4*)&dst[idx] = o;
  }
}

// ---------------------------------------------------------------------------
// NT GEMM: C[M,N] = A[M,K] * Wf[N,K]^T (+bias). 128x128 tile, BK=64,
// 8 waves (512 thr), wave grid 2x4 (64x32 out each).
// A: LDS double-buffer, gload16, counted vmcnt + raw s_barrier.
// B: fragment-native global -> register double-buffer across the barrier.
// EPI=0: qkv epilogue (Q pre-scaled [B,H,T,D]; K',V' fragment-native).
// EPI=1: plain f32 out.
// ---------------------------------------------------------------------------
template <int EPI, int NXT>
__global__ __launch_bounds__(512)
void gemm_nt(const _Float16* __restrict__ A, const _Float16* __restrict__ Bw,
             const float* __restrict__ bias,
             _Float16* __restrict__ qb, _Float16* __restrict__ kb,
             _Float16* __restrict__ vtb, float* __restrict__ outp) {
  __shared__ _Float16 As[2][128 * 64];
  const int tid = threadIdx.x;
  const int w = tid >> 6, lane = tid & 63;
  const int lr = lane & 15, lk = lane >> 4;

  const int id = blockIdx.x;
  const int xcd = id & 7, j = id >> 3;
  const int m0 = (xcd * 4 + j / NXT) * 128;  // 4 M-panels per XCD
  const int n0 = (j % NXT) * 128;
  const int wr = w >> 2, wc = w & 3;  // 2x4 wave grid; wave = 64x32 out

  f32x4 acc[4][2] = {};
  const char* Ab = (const char*)(A + (size_t)m0 * TK);
  const char* WB = (const char*)Bw;
  const int nb = (n0 >> 4) + wc * 2;
  constexpr int NS = TK / 64;  // 12 K-steps

  auto loadB = [&](int ks, f16x8 (&bf)[2][2]) {
#pragma unroll
    for (int ni = 0; ni < 2; ++ni)
#pragma unroll
      for (int kc = 0; kc < 2; ++kc)
        bf[ni][kc] = *(const f16x8*)(WB +
                                     ((size_t)(nb + ni) * 24 + ks * 2 + kc) * 1024 +
                                     lane * 16);
  };
  auto stageA = [&](int ks, int buf) {
#pragma unroll
    for (int c = 0; c < 2; ++c) {
      int g = w * 2 + c;  // chunk 0..15 of the 16 KB A tile
      int o = g * 1024 + lane * 16;
      int row = o >> 7, ch = (o >> 4) & 7;
      gload16(Ab + (size_t)row * (TK * 2) + ks * 128 + ((ch ^ (row & 7)) << 4),
              (char*)As[buf] + g * 1024);
    }
  };
  auto step = [&](f16x8 (&bc)[2][2], f16x8 (&bn)[2][2], int buf, int ks) {
    if (ks + 1 < NS) {
      loadB(ks + 1, bn);        // 4 reg loads, consumed next step
      stageA(ks + 1, buf ^ 1);  // 2 gload16
      asm volatile("s_waitcnt vmcnt(6)" ::: "memory");  // cur A+B landed
    } else {
      asm volatile("s_waitcnt vmcnt(0)" ::: "memory");
    }
    __builtin_amdgcn_s_barrier();
#pragma unroll
    for (int kc = 0; kc < 2; ++kc) {
      f16x8 af[4];
#pragma unroll
      for (int mi = 0; mi < 4; ++mi) {
        int row = wr * 64 + mi * 16 + lr;
        af[mi] =
            *(const f16x8*)&As[buf][row * 64 + (((kc * 4 + lk) ^ (row & 7)) << 3)];
      }
#pragma unroll
      for (int mi = 0; mi < 4; ++mi)
#pragma unroll
        for (int ni = 0; ni < 2; ++ni)
          acc[mi][ni] = __builtin_amdgcn_mfma_f32_16x16x32_f16(af[mi], bc[ni][kc],
                                                               acc[mi][ni], 0, 0, 0);
    }
    __builtin_amdgcn_s_barrier();  // all reads of As[buf] done before restage
  };

  f16x8 bA[2][2], bB[2][2];
  loadB(0, bA);
  stageA(0, 0);
  for (int kss = 0; kss < NS; kss += 2) {
    step(bA, bB, 0, kss);
    step(bB, bA, 1, kss + 1);
  }

  // epilogue: C layout col = lane&15 (N), row = (lane>>4)*4 + r
#pragma unroll
  for (int mi = 0; mi < 4; ++mi) {
#pragma unroll
    for (int ni = 0; ni < 2; ++ni) {
      const int col = n0 + wc * 32 + ni * 16 + lr;
#pragma unroll
      for (int r = 0; r < 4; ++r) {
        const int row = m0 + wr * 64 + mi * 16 + lk * 4 + r;
        float v = acc[mi][ni][r];
        if (EPI == 0) {
          v += bias[col];
          const int which = (col >= 2 * TE) ? 2 : (col >= TE ? 1 : 0);
          const int e = col - which * TE;
          const int h = e >> 6, d = e & 63;
          const int b = row >> 11, t = row & (TT - 1);
          const size_t hb = (size_t)(b * TH + h);
          if (which == 0) {
            qb[(hb * TT + t) * TD + d] = (_Float16)(v * SCALE_LOG2E);
          } else if (which == 1) {
            // K' fragment-native
            kb[((((hb * 128 + (t >> 4)) * 8 + (d >> 3)) * 16 + (t & 15)) * 8) +
               (d & 7)] = (_Float16)v;
          } else {
            // V' fragment-native
            const int kc = (t >> 5) & 1, hi = (t >> 4) & 1;
            const int lkv = (t >> 2) & 3, m = t & 3;
            vtb[((((((hb * 32 + (t >> 6)) * 4 + (d >> 4)) * 2 + kc) * 4 + lkv) *
                      16 +
                  (d & 15)) *
                 8) +
                (hi * 4 + m)] = (_Float16)v;
          }
        } else {
          outp[(size_t)row * TE + col] = v;
        }
      }
    }
  }
}

// ---------------------------------------------------------------------------
// Causal flash attention, reg-direct, WORK-STEALING blocks. 768 blocks x
// 4 waves; each block pulls units (bh, qt) = (u%24, 31-u/24) from a global
// atomic counter (heavy qt first) -> every CU keeps 12 resident waves busy
// until the global tail (fixes the R9 occupancy collapse: balanced work but
// unbalanced parallelism-over-time). Within a unit the 4 waves run the R7
// pipeline independently (wave w = q-rows t0+w*16..+15), sharing the KV
// tiles through L1 (4x reuse). K,V fragment-native -> coalesced 1KB wave
// loads to VGPR; kfA/kfB reg dbuf (K prefetched 2 tiles ahead), V at phase
// start. SWAPPED QK^T: lane-local softmax, P in registers. T13 defer-max.
// Two __syncthreads per ~17-phase unit (unit broadcast) -- amortized.
// ---------------------------------------------------------------------------
__global__ __launch_bounds__(256)
void attn_kernel(const _Float16* __restrict__ qbuf, const _Float16* __restrict__ kbuf,
                 const _Float16* __restrict__ vtbuf, _Float16* __restrict__ ob,
                 int* __restrict__ ctr) {
  __shared__ int s_unit;
  const int tid = threadIdx.x, w = tid >> 6, lane = tid & 63;
  const int lr = lane & 15, lk = lane >> 4;

  for (;;) {
    __syncthreads();  // protect s_unit from previous iteration's readers
    if (tid == 0) s_unit = atomicAdd(ctr, 1);
    __syncthreads();
    const int u = s_unit;
    if (u >= NUNITS) break;

    const int bh = u % 24;
    const int qt = 31 - u / 24;  // heavy units first
    const int t0 = qt * 64;
    const int nt = qt + 1, ntm1 = qt;

    const _Float16* q = qbuf + (size_t)bh * (TT * TD);  // [T][64], pre-scaled
    const char* kbase =
        (const char*)(kbuf + (size_t)bh * (TT * TD)) + lk * 256 + lr * 16;
    const char* vbase =
        (const char*)(vtbuf + (size_t)bh * (TT * TD)) + lk * 256 + lr * 16;

    f16x8 qf[2];  // B-operand: Q[q=t0+w*16+lr][kc*32+lk*8..]
#pragma unroll
    for (int kc = 0; kc < 2; ++kc)
      qf[kc] = *(const f16x8*)&q[(size_t)(t0 + w * 16 + lr) * TD + kc * 32 + lk * 8];

    f32x4 of[4] = {};                 // O[q=lk*4+r][d=nd*16+lr]
    float mrun = -1e30f, lrun = 0.f;  // softmax state (q = lane&15, x4 replicas)

    f16x8 kfA[2][4], kfB[2][4], vf[2][4];

#pragma unroll
    for (int kc = 0; kc < 2; ++kc)
#pragma unroll
      for (int ni = 0; ni < 4; ++ni)
        kfA[kc][ni] = *(const f16x8*)(kbase + ni * 2048 + kc * 1024);
    {
      const char* k1 = kbase + (size_t)(nt > 1 ? 1 : 0) * 8192;
#pragma unroll
      for (int kc = 0; kc < 2; ++kc)
#pragma unroll
        for (int ni = 0; ni < 4; ++ni)
          kfB[kc][ni] = *(const f16x8*)(k1 + ni * 2048 + kc * 1024);
    }

    auto phase = [&](f16x8 (&kf)[2][4], int st) {
      const char* vt = vbase + (size_t)st * 8192;  // V(st): cover=QK^T+softmax
#pragma unroll
      for (int kc = 0; kc < 2; ++kc)
#pragma unroll
        for (int nd = 0; nd < 4; ++nd)
          vf[kc][nd] = *(const f16x8*)(vt + nd * 2048 + kc * 1024);

      // S^T: sa[ni] = mfma(K, Q): lane holds S[s=st*64+ni*16+lk*4+r][q=lr]
      f32x4 sa[4] = {};
      __builtin_amdgcn_s_setprio(1);
#pragma unroll
      for (int kc = 0; kc < 2; ++kc)
#pragma unroll
        for (int ni = 0; ni < 4; ++ni)
          sa[ni] = __builtin_amdgcn_mfma_f32_16x16x32_f16(kf[kc][ni], qf[kc],
                                                          sa[ni], 0, 0, 0);
      __builtin_amdgcn_s_setprio(0);

      // prefetch K(st+2) into the buffer just consumed (clamped)
      {
        const int stp = (st + 2 <= ntm1) ? st + 2 : ntm1;
        const char* kt = kbase + (size_t)stp * 8192;
#pragma unroll
        for (int kc = 0; kc < 2; ++kc)
#pragma unroll
          for (int ni = 0; ni < 4; ++ni)
            kf[kc][ni] = *(const f16x8*)(kt + ni * 2048 + kc * 1024);
      }

      if (st == ntm1) {  // diagonal tile: causal mask (s > q)
        const int s0 = st * 64;
#pragma unroll
        for (int ni = 0; ni < 4; ++ni)
#pragma unroll
          for (int r = 0; r < 4; ++r)
            if (s0 + ni * 16 + lk * 4 + r > t0 + w * 16 + lr) sa[ni][r] = -1e30f;
      }

      // lane-local row max, reduce over the 4 replica lanes
      float mx;
      {
        float a0 = fmaxf(fmaxf(sa[0][0], sa[0][1]), fmaxf(sa[0][2], sa[0][3]));
        float a1 = fmaxf(fmaxf(sa[1][0], sa[1][1]), fmaxf(sa[1][2], sa[1][3]));
        float a2 = fmaxf(fmaxf(sa[2][0], sa[2][1]), fmaxf(sa[2][2], sa[2][3]));
        float a3 = fmaxf(fmaxf(sa[3][0], sa[3][1]), fmaxf(sa[3][2], sa[3][3]));
        mx = fmaxf(fmaxf(a0, a1), fmaxf(a2, a3));
        mx = fmaxf(mx, __shfl_xor(mx, 16));
        mx = fmaxf(mx, __shfl_xor(mx, 32));
      }

      if (__any(mx > mrun + 8.0f)) {  // defer-max
        float mn = fmaxf(mrun, mx);
        float al = __builtin_amdgcn_exp2f(mrun - mn);
        mrun = mn;
        lrun *= al;
        float al4[4];
#pragma unroll
        for (int r = 0; r < 4; ++r) al4[r] = __shfl(al, lk * 4 + r);
#pragma unroll
        for (int nd = 0; nd < 4; ++nd)
#pragma unroll
          for (int r = 0; r < 4; ++r) of[nd][r] *= al4[r];
      }

      // P = exp2(sa - mrun); pack pa[kc] slot 4*hi+m <-> s=32kc+16hi+4lk+m
      f16x8 pa[2];
      float rs;
      {
        float rn[4];
#pragma unroll
        for (int ni = 0; ni < 4; ++ni) {
          float p0 = __builtin_amdgcn_exp2f(sa[ni][0] - mrun);
          float p1 = __builtin_amdgcn_exp2f(sa[ni][1] - mrun);
          float p2 = __builtin_amdgcn_exp2f(sa[ni][2] - mrun);
          float p3 = __builtin_amdgcn_exp2f(sa[ni][3] - mrun);
          rn[ni] = (p0 + p1) + (p2 + p3);
          pa[ni >> 1][(ni & 1) * 4 + 0] = (_Float16)p0;
          pa[ni >> 1][(ni & 1) * 4 + 1] = (_Float16)p1;
          pa[ni >> 1][(ni & 1) * 4 + 2] = (_Float16)p2;
          pa[ni >> 1][(ni & 1) * 4 + 3] = (_Float16)p3;
        }
        rs = (rn[0] + rn[1]) + (rn[2] + rn[3]);
        rs += __shfl_xor(rs, 16);
        rs += __shfl_xor(rs, 32);
      }
      lrun += rs;

      // O += P V
      __builtin_amdgcn_s_setprio(1);
#pragma unroll
      for (int kc = 0; kc < 2; ++kc)
#pragma unroll
        for (int nd = 0; nd < 4; ++nd)
          of[nd] = __builtin_amdgcn_mfma_f32_16x16x32_f16(pa[kc], vf[kc][nd],
                                                          of[nd], 0, 0, 0);
      __builtin_amdgcn_s_setprio(0);
    };

    int st = 0;
    while (st + 1 < nt) {
      phase(kfA, st);
      phase(kfB, st + 1);
      st += 2;
    }
    if (st < nt) phase(kfA, st);

    // epilogue: lrun owner lane lr = q (x4 replicas)
    float linv[4];
#pragma unroll
    for (int r = 0; r < 4; ++r) linv[r] = __shfl(lrun, lk * 4 + r);
    const int b = bh / TH, h = bh - b * TH;
#pragma unroll
    for (int nd = 0; nd < 4; ++nd) {
#pragma unroll
      for (int r = 0; r < 4; ++r) {
        int tg = t0 + w * 16 + lk * 4 + r;
        int d = nd * 16 + lr;
        ob[(size_t)(b * TT + tg) * TE + h * TD + d] =
            (_Float16)(of[nd][r] / linv[r]);
      }
    }
  }
}

// ---------------------------------------------------------------------------
extern "C" void kernel_launch(void* const* d_in, const int* in_sizes, int n_in,
                              void* d_out, int out_size, void* d_ws, size_t ws_size,
                              hipStream_t stream) {
  const float* x    = (const float*)d_in[0];
  const float* wqkv = (const float*)d_in[1];
  const float* bqkv = (const float*)d_in[2];
  const float* wfin = (const float*)d_in[3];
  float* out = (float*)d_out;

  _Float16* xh  = (_Float16*)d_ws;          // [4096][768] row-major
  _Float16* wqh = xh + (size_t)TM * TK;     // fragment-native Wf
  _Float16* wfh = wqh + (size_t)NQKV * TK;  // fragment-native Wf
  _Float16* qb  = wfh + (size_t)TE * TE;    // [B,H,T,D] (pre-scaled)
  _Float16* kb  = qb + (size_t)TM * TE;     // K' fragment-native
  _Float16* vtb = kb + (size_t)TM * TE;     // V' fragment-native
  _Float16* ob  = vtb + (size_t)TM * TE;    // [4096][768] attn output
  int* ctr = (int*)(ob + (size_t)TM * TE);  // work-steal counter

  hipMemsetAsync(ctr, 0, 4, stream);
  cvt3<<<5376, 256, 0, stream>>>(x, wqkv, wfin, xh, wqh, wfh);
  gemm_nt<0, NQKV / 128><<<(NQKV / 128) * (TM / 128), 512, 0, stream>>>(
      xh, wqh, bqkv, qb, kb, vtb, nullptr);
  attn_kernel<<<dim3(TT / 64 * TB * TH), 256, 0, stream>>>(qb, kb, vtb, ob, ctr);
  gemm_nt<1, TE / 128><<<(TE / 128) * (TM / 128), 512, 0, stream>>>(
      ob, wfh, nullptr, nullptr, nullptr, nullptr, out);
}

// Round 12
// 99.627 us; speedup vs baseline: 1.0301x; 1.0301x over previous
//
#include <hip/hip_runtime.h>
#include <cstdint>

typedef _Float16 f16x8 __attribute__((ext_vector_type(8)));
typedef _Float16 f16x4 __attribute__((ext_vector_type(4)));
typedef float    f32x4 __attribute__((ext_vector_type(4)));

static constexpr int TB = 2;
static constexpr int TT = 2048;
static constexpr int TE = 768;
static constexpr int TH = 12;
static constexpr int TD = 64;
static constexpr int TM = TB * TT;      // 4096 rows (B*T)
static constexpr int TK = TE;           // 768 (K for both GEMMs)
static constexpr int NQKV = 3 * TE;     // 2304

#define SCALE_LOG2E 0.18033688011112042f  /* (1/sqrt(64)) * log2(e) */

// async global->LDS, 16B per lane. LDS dest is wave-uniform base + lane*16.
__device__ __forceinline__ void gload16(const void* g, void* lds) {
  __builtin_amdgcn_global_load_lds(
      (__attribute__((address_space(1))) void*)(uintptr_t)g,
      (__attribute__((address_space(3))) void*)(uint32_t)(uintptr_t)lds, 16, 0, 0);
}

// ---------------------------------------------------------------------------
// f32 -> f16 convert. x -> row-major f16. w_qkv / w_final -> FRAGMENT-NATIVE
// Wf layout: f16 idx(n,k) = ((n>>4)*24 + (k>>5))*512 + ((k>>3)&3)*128
//                           + (n&15)*8 + (k&7)
// ---------------------------------------------------------------------------
__global__ void cvt3(const float* __restrict__ x, const float* __restrict__ wq,
                     const float* __restrict__ wf, _Float16* __restrict__ xh,
                     _Float16* __restrict__ wqh, _Float16* __restrict__ wfh) {
  const int NX = TM * TK / 4, NW = NQKV * TK / 4;
  int i = blockIdx.x * 256 + threadIdx.x;
  if (i < NX) {
    float4 v = ((const float4*)x)[i];
    f16x4 o = {(_Float16)v.x, (_Float16)v.y, (_Float16)v.z, (_Float16)v.w};
    *(f16x4*)&xh[(size_t)i * 4] = o;
  } else {
    const float4* src; _Float16* dst; int j;
    if (i < NX + NW) { src = (const float4*)wq; dst = wqh; j = i - NX; }
    else             { src = (const float4*)wf; dst = wfh; j = i - NX - NW; }
    float4 v = src[j];
    f16x4 o = {(_Float16)v.x, (_Float16)v.y, (_Float16)v.z, (_Float16)v.w};
    const int flat = j * 4;
    const int n = flat / TK, k = flat % TK;
    const size_t idx = ((size_t)(n >> 4) * 24 + (k >> 5)) * 512 +
                       ((k >> 3) & 3) * 128 + (n & 15) * 8 + (k & 7);
    *(f16x4*)&dst[idx] = o;
  }
}

// ---------------------------------------------------------------------------
// NT GEMM: C[M,N] = A[M,K] * Wf[N,K]^T (+bias). 128x128 tile, BK=64,
// 8 waves (512 thr), wave grid 2x4 (64x32 out each).
// A: LDS double-buffer, gload16, counted vmcnt + raw s_barrier.
// B: fragment-native global -> register double-buffer across the barrier.
// EPI=0: qkv epilogue (Q pre-scaled [B,H,T,D]; K',V' fragment-native).
// EPI=1: plain f32 out.
// ---------------------------------------------------------------------------
template <int EPI, int NXT>
__global__ __launch_bounds__(512)
void gemm_nt(const _Float16* __restrict__ A, const _Float16* __restrict__ Bw,
             const float* __restrict__ bias,
             _Float16* __restrict__ qb, _Float16* __restrict__ kb,
             _Float16* __restrict__ vtb, float* __restrict__ outp) {
  __shared__ _Float16 As[2][128 * 64];
  const int tid = threadIdx.x;
  const int w = tid >> 6, lane = tid & 63;
  const int lr = lane & 15, lk = lane >> 4;

  const int id = blockIdx.x;
  const int xcd = id & 7, j = id >> 3;
  const int m0 = (xcd * 4 + j / NXT) * 128;  // 4 M-panels per XCD
  const int n0 = (j % NXT) * 128;
  const int wr = w >> 2, wc = w & 3;  // 2x4 wave grid; wave = 64x32 out

  f32x4 acc[4][2] = {};
  const char* Ab = (const char*)(A + (size_t)m0 * TK);
  const char* WB = (const char*)Bw;
  const int nb = (n0 >> 4) + wc * 2;
  constexpr int NS = TK / 64;  // 12 K-steps

  auto loadB = [&](int ks, f16x8 (&bf)[2][2]) {
#pragma unroll
    for (int ni = 0; ni < 2; ++ni)
#pragma unroll
      for (int kc = 0; kc < 2; ++kc)
        bf[ni][kc] = *(const f16x8*)(WB +
                                     ((size_t)(nb + ni) * 24 + ks * 2 + kc) * 1024 +
                                     lane * 16);
  };
  auto stageA = [&](int ks, int buf) {
#pragma unroll
    for (int c = 0; c < 2; ++c) {
      int g = w * 2 + c;  // chunk 0..15 of the 16 KB A tile
      int o = g * 1024 + lane * 16;
      int row = o >> 7, ch = (o >> 4) & 7;
      gload16(Ab + (size_t)row * (TK * 2) + ks * 128 + ((ch ^ (row & 7)) << 4),
              (char*)As[buf] + g * 1024);
    }
  };
  auto step = [&](f16x8 (&bc)[2][2], f16x8 (&bn)[2][2], int buf, int ks) {
    if (ks + 1 < NS) {
      loadB(ks + 1, bn);        // 4 reg loads, consumed next step
      stageA(ks + 1, buf ^ 1);  // 2 gload16
      asm volatile("s_waitcnt vmcnt(6)" ::: "memory");  // cur A+B landed
    } else {
      asm volatile("s_waitcnt vmcnt(0)" ::: "memory");
    }
    __builtin_amdgcn_s_barrier();
#pragma unroll
    for (int kc = 0; kc < 2; ++kc) {
      f16x8 af[4];
#pragma unroll
      for (int mi = 0; mi < 4; ++mi) {
        int row = wr * 64 + mi * 16 + lr;
        af[mi] =
            *(const f16x8*)&As[buf][row * 64 + (((kc * 4 + lk) ^ (row & 7)) << 3)];
      }
#pragma unroll
      for (int mi = 0; mi < 4; ++mi)
#pragma unroll
        for (int ni = 0; ni < 2; ++ni)
          acc[mi][ni] = __builtin_amdgcn_mfma_f32_16x16x32_f16(af[mi], bc[ni][kc],
                                                               acc[mi][ni], 0, 0, 0);
    }
    __builtin_amdgcn_s_barrier();  // all reads of As[buf] done before restage
  };

  f16x8 bA[2][2], bB[2][2];
  loadB(0, bA);
  stageA(0, 0);
  for (int kss = 0; kss < NS; kss += 2) {
    step(bA, bB, 0, kss);
    step(bB, bA, 1, kss + 1);
  }

  // epilogue: C layout col = lane&15 (N), row = (lane>>4)*4 + r
#pragma unroll
  for (int mi = 0; mi < 4; ++mi) {
#pragma unroll
    for (int ni = 0; ni < 2; ++ni) {
      const int col = n0 + wc * 32 + ni * 16 + lr;
#pragma unroll
      for (int r = 0; r < 4; ++r) {
        const int row = m0 + wr * 64 + mi * 16 + lk * 4 + r;
        float v = acc[mi][ni][r];
        if (EPI == 0) {
          v += bias[col];
          const int which = (col >= 2 * TE) ? 2 : (col >= TE ? 1 : 0);
          const int e = col - which * TE;
          const int h = e >> 6, d = e & 63;
          const int b = row >> 11, t = row & (TT - 1);
          const size_t hb = (size_t)(b * TH + h);
          if (which == 0) {
            qb[(hb * TT + t) * TD + d] = (_Float16)(v * SCALE_LOG2E);
          } else if (which == 1) {
            // K' fragment-native
            kb[((((hb * 128 + (t >> 4)) * 8 + (d >> 3)) * 16 + (t & 15)) * 8) +
               (d & 7)] = (_Float16)v;
          } else {
            // V' fragment-native
            const int kc = (t >> 5) & 1, hi = (t >> 4) & 1;
            const int lkv = (t >> 2) & 3, m = t & 3;
            vtb[((((((hb * 32 + (t >> 6)) * 4 + (d >> 4)) * 2 + kc) * 4 + lkv) *
                      16 +
                  (d & 15)) *
                 8) +
                (hi * 4 + m)] = (_Float16)v;
          }
        } else {
          outp[(size_t)row * TE + col] = v;
        }
      }
    }
  }
}

// ---------------------------------------------------------------------------
// Causal flash attention, reg-direct, PER-XCD WORK QUEUES. 768 blocks x
// 4 waves. Queue x (x = blockIdx.x & 7, the %8 XCD mapping measured in the
// gemm chunking) holds the 96 units of heads {x, x+8, x+16} ordered heavy-
// qt-first; its 96 blocks pull via a per-XCD atomic. -> R11's temporal
// balance (stealing) WITH R7's L2 locality (per-XCD KV set = 1.5MB << 4MB).
// Within a unit the 4 waves run the R7 pipeline independently (wave w =
// q-rows t0+w*16..+15), sharing KV tiles through L1. K,V fragment-native ->
// coalesced 1KB wave loads to VGPR; kfA/kfB reg dbuf (K prefetched 2 tiles
// ahead), V at phase start. SWAPPED QK^T: lane-local softmax, P in
// registers. T13 defer-max (thr=8, log2 domain).
// ---------------------------------------------------------------------------
__global__ __launch_bounds__(256)
void attn_kernel(const _Float16* __restrict__ qbuf, const _Float16* __restrict__ kbuf,
                 const _Float16* __restrict__ vtbuf, _Float16* __restrict__ ob,
                 int* __restrict__ ctr) {
  __shared__ int s_unit;
  const int tid = threadIdx.x, w = tid >> 6, lane = tid & 63;
  const int lr = lane & 15, lk = lane >> 4;
  const int xcd = blockIdx.x & 7;
  int* myctr = ctr + xcd;

  for (;;) {
    __syncthreads();  // protect s_unit from previous iteration's readers
    if (tid == 0) s_unit = atomicAdd(myctr, 1);
    __syncthreads();
    const int u = s_unit;
    if (u >= 96) break;

    const int bh = xcd + 8 * (u % 3);  // heads {x, x+8, x+16} only
    const int qt = 31 - u / 3;         // heavy units first
    const int t0 = qt * 64;
    const int nt = qt + 1, ntm1 = qt;

    const _Float16* q = qbuf + (size_t)bh * (TT * TD);  // [T][64], pre-scaled
    const char* kbase =
        (const char*)(kbuf + (size_t)bh * (TT * TD)) + lk * 256 + lr * 16;
    const char* vbase =
        (const char*)(vtbuf + (size_t)bh * (TT * TD)) + lk * 256 + lr * 16;

    f16x8 qf[2];  // B-operand: Q[q=t0+w*16+lr][kc*32+lk*8..]
#pragma unroll
    for (int kc = 0; kc < 2; ++kc)
      qf[kc] = *(const f16x8*)&q[(size_t)(t0 + w * 16 + lr) * TD + kc * 32 + lk * 8];

    f32x4 of[4] = {};                 // O[q=lk*4+r][d=nd*16+lr]
    float mrun = -1e30f, lrun = 0.f;  // softmax state (q = lane&15, x4 replicas)

    f16x8 kfA[2][4], kfB[2][4], vf[2][4];

#pragma unroll
    for (int kc = 0; kc < 2; ++kc)
#pragma unroll
      for (int ni = 0; ni < 4; ++ni)
        kfA[kc][ni] = *(const f16x8*)(kbase + ni * 2048 + kc * 1024);
    {
      const char* k1 = kbase + (size_t)(nt > 1 ? 1 : 0) * 8192;
#pragma unroll
      for (int kc = 0; kc < 2; ++kc)
#pragma unroll
        for (int ni = 0; ni < 4; ++ni)
          kfB[kc][ni] = *(const f16x8*)(k1 + ni * 2048 + kc * 1024);
    }

    auto phase = [&](f16x8 (&kf)[2][4], int st) {
      const char* vt = vbase + (size_t)st * 8192;  // V(st): cover=QK^T+softmax
#pragma unroll
      for (int kc = 0; kc < 2; ++kc)
#pragma unroll
        for (int nd = 0; nd < 4; ++nd)
          vf[kc][nd] = *(const f16x8*)(vt + nd * 2048 + kc * 1024);

      // S^T: sa[ni] = mfma(K, Q): lane holds S[s=st*64+ni*16+lk*4+r][q=lr]
      f32x4 sa[4] = {};
      __builtin_amdgcn_s_setprio(1);
#pragma unroll
      for (int kc = 0; kc < 2; ++kc)
#pragma unroll
        for (int ni = 0; ni < 4; ++ni)
          sa[ni] = __builtin_amdgcn_mfma_f32_16x16x32_f16(kf[kc][ni], qf[kc],
                                                          sa[ni], 0, 0, 0);
      __builtin_amdgcn_s_setprio(0);

      // prefetch K(st+2) into the buffer just consumed (clamped)
      {
        const int stp = (st + 2 <= ntm1) ? st + 2 : ntm1;
        const char* kt = kbase + (size_t)stp * 8192;
#pragma unroll
        for (int kc = 0; kc < 2; ++kc)
#pragma unroll
          for (int ni = 0; ni < 4; ++ni)
            kf[kc][ni] = *(const f16x8*)(kt + ni * 2048 + kc * 1024);
      }

      if (st == ntm1) {  // diagonal tile: causal mask (s > q)
        const int s0 = st * 64;
#pragma unroll
        for (int ni = 0; ni < 4; ++ni)
#pragma unroll
          for (int r = 0; r < 4; ++r)
            if (s0 + ni * 16 + lk * 4 + r > t0 + w * 16 + lr) sa[ni][r] = -1e30f;
      }

      // lane-local row max, reduce over the 4 replica lanes
      float mx;
      {
        float a0 = fmaxf(fmaxf(sa[0][0], sa[0][1]), fmaxf(sa[0][2], sa[0][3]));
        float a1 = fmaxf(fmaxf(sa[1][0], sa[1][1]), fmaxf(sa[1][2], sa[1][3]));
        float a2 = fmaxf(fmaxf(sa[2][0], sa[2][1]), fmaxf(sa[2][2], sa[2][3]));
        float a3 = fmaxf(fmaxf(sa[3][0], sa[3][1]), fmaxf(sa[3][2], sa[3][3]));
        mx = fmaxf(fmaxf(a0, a1), fmaxf(a2, a3));
        mx = fmaxf(mx, __shfl_xor(mx, 16));
        mx = fmaxf(mx, __shfl_xor(mx, 32));
      }

      if (__any(mx > mrun + 8.0f)) {  // defer-max
        float mn = fmaxf(mrun, mx);
        float al = __builtin_amdgcn_exp2f(mrun - mn);
        mrun = mn;
        lrun *= al;
        float al4[4];
#pragma unroll
        for (int r = 0; r < 4; ++r) al4[r] = __shfl(al, lk * 4 + r);
#pragma unroll
        for (int nd = 0; nd < 4; ++nd)
#pragma unroll
          for (int r = 0; r < 4; ++r) of[nd][r] *= al4[r];
      }

      // P = exp2(sa - mrun); pack pa[kc] slot 4*hi+m <-> s=32kc+16hi+4lk+m
      f16x8 pa[2];
      float rs;
      {
        float rn[4];
#pragma unroll
        for (int ni = 0; ni < 4; ++ni) {
          float p0 = __builtin_amdgcn_exp2f(sa[ni][0] - mrun);
          float p1 = __builtin_amdgcn_exp2f(sa[ni][1] - mrun);
          float p2 = __builtin_amdgcn_exp2f(sa[ni][2] - mrun);
          float p3 = __builtin_amdgcn_exp2f(sa[ni][3] - mrun);
          rn[ni] = (p0 + p1) + (p2 + p3);
          pa[ni >> 1][(ni & 1) * 4 + 0] = (_Float16)p0;
          pa[ni >> 1][(ni & 1) * 4 + 1] = (_Float16)p1;
          pa[ni >> 1][(ni & 1) * 4 + 2] = (_Float16)p2;
          pa[ni >> 1][(ni & 1) * 4 + 3] = (_Float16)p3;
        }
        rs = (rn[0] + rn[1]) + (rn[2] + rn[3]);
        rs += __shfl_xor(rs, 16);
        rs += __shfl_xor(rs, 32);
      }
      lrun += rs;

      // O += P V
      __builtin_amdgcn_s_setprio(1);
#pragma unroll
      for (int kc = 0; kc < 2; ++kc)
#pragma unroll
        for (int nd = 0; nd < 4; ++nd)
          of[nd] = __builtin_amdgcn_mfma_f32_16x16x32_f16(pa[kc], vf[kc][nd],
                                                          of[nd], 0, 0, 0);
      __builtin_amdgcn_s_setprio(0);
    };

    int st = 0;
    while (st + 1 < nt) {
      phase(kfA, st);
      phase(kfB, st + 1);
      st += 2;
    }
    if (st < nt) phase(kfA, st);

    // epilogue: lrun owner lane lr = q (x4 replicas)
    float linv[4];
#pragma unroll
    for (int r = 0; r < 4; ++r) linv[r] = __shfl(lrun, lk * 4 + r);
    const int b = bh / TH, h = bh - b * TH;
#pragma unroll
    for (int nd = 0; nd < 4; ++nd) {
#pragma unroll
      for (int r = 0; r < 4; ++r) {
        int tg = t0 + w * 16 + lk * 4 + r;
        int d = nd * 16 + lr;
        ob[(size_t)(b * TT + tg) * TE + h * TD + d] =
            (_Float16)(of[nd][r] / linv[r]);
      }
    }
  }
}

// ---------------------------------------------------------------------------
extern "C" void kernel_launch(void* const* d_in, const int* in_sizes, int n_in,
                              void* d_out, int out_size, void* d_ws, size_t ws_size,
                              hipStream_t stream) {
  const float* x    = (const float*)d_in[0];
  const float* wqkv = (const float*)d_in[1];
  const float* bqkv = (const float*)d_in[2];
  const float* wfin = (const float*)d_in[3];
  float* out = (float*)d_out;

  _Float16* xh  = (_Float16*)d_ws;          // [4096][768] row-major
  _Float16* wqh = xh + (size_t)TM * TK;     // fragment-native Wf
  _Float16* wfh = wqh + (size_t)NQKV * TK;  // fragment-native Wf
  _Float16* qb  = wfh + (size_t)TE * TE;    // [B,H,T,D] (pre-scaled)
  _Float16* kb  = qb + (size_t)TM * TE;     // K' fragment-native
  _Float16* vtb = kb + (size_t)TM * TE;     // V' fragment-native
  _Float16* ob  = vtb + (size_t)TM * TE;    // [4096][768] attn output
  int* ctr = (int*)(ob + (size_t)TM * TE);  // 8 per-XCD work counters

  hipMemsetAsync(ctr, 0, 32, stream);
  cvt3<<<5376, 256, 0, stream>>>(x, wqkv, wfin, xh, wqh, wfh);
  gemm_nt<0, NQKV / 128><<<(NQKV / 128) * (TM / 128), 512, 0, stream>>>(
      xh, wqh, bqkv, qb, kb, vtb, nullptr);
  attn_kernel<<<dim3(TT / 64 * TB * TH), 256, 0, stream>>>(qb, kb, vtb, ob, ctr);
  gemm_nt<1, TE / 128><<<(TE / 128) * (TM / 128), 512, 0, stream>>>(
      ob, wfh, nullptr, nullptr, nullptr, nullptr, out);
}

// Round 13
// 87.800 us; speedup vs baseline: 1.1689x; 1.1347x over previous
//
#include <hip/hip_runtime.h>
#include <cstdint>

typedef _Float16 f16x8 __attribute__((ext_vector_type(8)));
typedef _Float16 f16x4 __attribute__((ext_vector_type(4)));
typedef float    f32x4 __attribute__((ext_vector_type(4)));

static constexpr int TB = 2;
static constexpr int TT = 2048;
static constexpr int TE = 768;
static constexpr int TH = 12;
static constexpr int TD = 64;
static constexpr int TM = TB * TT;      // 4096 rows (B*T)
static constexpr int TK = TE;           // 768 (K for both GEMMs)
static constexpr int NQKV = 3 * TE;     // 2304

#define SCALE_LOG2E 0.18033688011112042f  /* (1/sqrt(64)) * log2(e) */

// async global->LDS, 16B per lane. LDS dest is wave-uniform base + lane*16.
__device__ __forceinline__ void gload16(const void* g, void* lds) {
  __builtin_amdgcn_global_load_lds(
      (__attribute__((address_space(1))) void*)(uintptr_t)g,
      (__attribute__((address_space(3))) void*)(uint32_t)(uintptr_t)lds, 16, 0, 0);
}

// ---------------------------------------------------------------------------
// f32 -> f16 convert. x -> row-major f16. w_qkv / w_final -> FRAGMENT-NATIVE
// Wf layout: f16 idx(n,k) = ((n>>4)*24 + (k>>5))*512 + ((k>>3)&3)*128
//                           + (n&15)*8 + (k&7)
// ---------------------------------------------------------------------------
__global__ void cvt3(const float* __restrict__ x, const float* __restrict__ wq,
                     const float* __restrict__ wf, _Float16* __restrict__ xh,
                     _Float16* __restrict__ wqh, _Float16* __restrict__ wfh) {
  const int NX = TM * TK / 4, NW = NQKV * TK / 4;
  int i = blockIdx.x * 256 + threadIdx.x;
  if (i < NX) {
    float4 v = ((const float4*)x)[i];
    f16x4 o = {(_Float16)v.x, (_Float16)v.y, (_Float16)v.z, (_Float16)v.w};
    *(f16x4*)&xh[(size_t)i * 4] = o;
  } else {
    const float4* src; _Float16* dst; int j;
    if (i < NX + NW) { src = (const float4*)wq; dst = wqh; j = i - NX; }
    else             { src = (const float4*)wf; dst = wfh; j = i - NX - NW; }
    float4 v = src[j];
    f16x4 o = {(_Float16)v.x, (_Float16)v.y, (_Float16)v.z, (_Float16)v.w};
    const int flat = j * 4;
    const int n = flat / TK, k = flat % TK;
    const size_t idx = ((size_t)(n >> 4) * 24 + (k >> 5)) * 512 +
                       ((k >> 3) & 3) * 128 + (n & 15) * 8 + (k & 7);
    *(f16x4*)&dst[idx] = o;
  }
}

// ---------------------------------------------------------------------------
// NT GEMM: C[M,N] = A[M,K] * Wf[N,K]^T (+bias). 128x128 tile, BK=64,
// 8 waves (512 thr), wave grid 2x4 (64x32 out each).
// A: LDS double-buffer, gload16, counted vmcnt + raw s_barrier.
// B: fragment-native global -> register double-buffer across the barrier.
// EPI=0: qkv epilogue (Q pre-scaled [B,H,T,D]; K',V' fragment-native).
// EPI=1: plain f32 out.
// ---------------------------------------------------------------------------
template <int EPI, int NXT>
__global__ __launch_bounds__(512)
void gemm_nt(const _Float16* __restrict__ A, const _Float16* __restrict__ Bw,
             const float* __restrict__ bias,
             _Float16* __restrict__ qb, _Float16* __restrict__ kb,
             _Float16* __restrict__ vtb, float* __restrict__ outp) {
  __shared__ _Float16 As[2][128 * 64];
  const int tid = threadIdx.x;
  const int w = tid >> 6, lane = tid & 63;
  const int lr = lane & 15, lk = lane >> 4;

  const int id = blockIdx.x;
  const int xcd = id & 7, j = id >> 3;
  const int m0 = (xcd * 4 + j / NXT) * 128;  // 4 M-panels per XCD
  const int n0 = (j % NXT) * 128;
  const int wr = w >> 2, wc = w & 3;  // 2x4 wave grid; wave = 64x32 out

  f32x4 acc[4][2] = {};
  const char* Ab = (const char*)(A + (size_t)m0 * TK);
  const char* WB = (const char*)Bw;
  const int nb = (n0 >> 4) + wc * 2;
  constexpr int NS = TK / 64;  // 12 K-steps

  auto loadB = [&](int ks, f16x8 (&bf)[2][2]) {
#pragma unroll
    for (int ni = 0; ni < 2; ++ni)
#pragma unroll
      for (int kc = 0; kc < 2; ++kc)
        bf[ni][kc] = *(const f16x8*)(WB +
                                     ((size_t)(nb + ni) * 24 + ks * 2 + kc) * 1024 +
                                     lane * 16);
  };
  auto stageA = [&](int ks, int buf) {
#pragma unroll
    for (int c = 0; c < 2; ++c) {
      int g = w * 2 + c;  // chunk 0..15 of the 16 KB A tile
      int o = g * 1024 + lane * 16;
      int row = o >> 7, ch = (o >> 4) & 7;
      gload16(Ab + (size_t)row * (TK * 2) + ks * 128 + ((ch ^ (row & 7)) << 4),
              (char*)As[buf] + g * 1024);
    }
  };
  auto step = [&](f16x8 (&bc)[2][2], f16x8 (&bn)[2][2], int buf, int ks) {
    if (ks + 1 < NS) {
      loadB(ks + 1, bn);        // 4 reg loads, consumed next step
      stageA(ks + 1, buf ^ 1);  // 2 gload16
      asm volatile("s_waitcnt vmcnt(6)" ::: "memory");  // cur A+B landed
    } else {
      asm volatile("s_waitcnt vmcnt(0)" ::: "memory");
    }
    __builtin_amdgcn_s_barrier();
#pragma unroll
    for (int kc = 0; kc < 2; ++kc) {
      f16x8 af[4];
#pragma unroll
      for (int mi = 0; mi < 4; ++mi) {
        int row = wr * 64 + mi * 16 + lr;
        af[mi] =
            *(const f16x8*)&As[buf][row * 64 + (((kc * 4 + lk) ^ (row & 7)) << 3)];
      }
#pragma unroll
      for (int mi = 0; mi < 4; ++mi)
#pragma unroll
        for (int ni = 0; ni < 2; ++ni)
          acc[mi][ni] = __builtin_amdgcn_mfma_f32_16x16x32_f16(af[mi], bc[ni][kc],
                                                               acc[mi][ni], 0, 0, 0);
    }
    __builtin_amdgcn_s_barrier();  // all reads of As[buf] done before restage
  };

  f16x8 bA[2][2], bB[2][2];
  loadB(0, bA);
  stageA(0, 0);
  for (int kss = 0; kss < NS; kss += 2) {
    step(bA, bB, 0, kss);
    step(bB, bA, 1, kss + 1);
  }

  // epilogue: C layout col = lane&15 (N), row = (lane>>4)*4 + r
#pragma unroll
  for (int mi = 0; mi < 4; ++mi) {
#pragma unroll
    for (int ni = 0; ni < 2; ++ni) {
      const int col = n0 + wc * 32 + ni * 16 + lr;
#pragma unroll
      for (int r = 0; r < 4; ++r) {
        const int row = m0 + wr * 64 + mi * 16 + lk * 4 + r;
        float v = acc[mi][ni][r];
        if (EPI == 0) {
          v += bias[col];
          const int which = (col >= 2 * TE) ? 2 : (col >= TE ? 1 : 0);
          const int e = col - which * TE;
          const int h = e >> 6, d = e & 63;
          const int b = row >> 11, t = row & (TT - 1);
          const size_t hb = (size_t)(b * TH + h);
          if (which == 0) {
            qb[(hb * TT + t) * TD + d] = (_Float16)(v * SCALE_LOG2E);
          } else if (which == 1) {
            // K' fragment-native
            kb[((((hb * 128 + (t >> 4)) * 8 + (d >> 3)) * 16 + (t & 15)) * 8) +
               (d & 7)] = (_Float16)v;
          } else {
            // V' fragment-native
            const int kc = (t >> 5) & 1, hi = (t >> 4) & 1;
            const int lkv = (t >> 2) & 3, m = t & 3;
            vtb[((((((hb * 32 + (t >> 6)) * 4 + (d >> 4)) * 2 + kc) * 4 + lkv) *
                      16 +
                  (d & 15)) *
                 8) +
                (hi * 4 + m)] = (_Float16)v;
          }
        } else {
          outp[(size_t)row * TE + col] = v;
        }
      }
    }
  }
}

// ---------------------------------------------------------------------------
// Causal flash attention, BARRIER-FREE, NO LDS (R7 config — best measured).
// Grid 768 = 24 heads x 32 q-tiles (bh = id%24, qt = 31 - id/24: balanced
// per CU, heavy first). 4 independent waves/block; wave w owns 16 q-rows.
// K,V fragment-native global -> every fragment a contiguous 1KB wave load
// to VGPR; kfA/kfB register dbuf, K prefetched 2 tiles ahead, V issued at
// phase start. 4 waves share tiles through L1. SWAPPED QK^T (mfma(K,Q)):
// lane-local softmax; P never leaves registers. T13 defer-max (thr=8).
// ---------------------------------------------------------------------------
__global__ __launch_bounds__(256)
void attn_kernel(const _Float16* __restrict__ qbuf, const _Float16* __restrict__ kbuf,
                 const _Float16* __restrict__ vtbuf, _Float16* __restrict__ ob) {
  const int tid = threadIdx.x, w = tid >> 6, lane = tid & 63;
  const int lr = lane & 15, lk = lane >> 4;

  const int id = blockIdx.x;        // 0..767
  const int bh = id % 24;
  const int qt = 31 - id / 24;      // heavy first, balanced per CU
  const int t0 = qt * 64;
  const int nt = qt + 1, ntm1 = qt;

  const _Float16* q = qbuf + (size_t)bh * (TT * TD);  // [T][64], pre-scaled
  const char* kbase =
      (const char*)(kbuf + (size_t)bh * (TT * TD)) + lk * 256 + lr * 16;
  const char* vbase =
      (const char*)(vtbuf + (size_t)bh * (TT * TD)) + lk * 256 + lr * 16;

  f16x8 qf[2];  // B-operand: Q[q=t0+w*16+lr][kc*32+lk*8 ..]
#pragma unroll
  for (int kc = 0; kc < 2; ++kc)
    qf[kc] = *(const f16x8*)&q[(size_t)(t0 + w * 16 + lr) * TD + kc * 32 + lk * 8];

  f32x4 of[4] = {};                 // O[q=lk*4+r][d=nd*16+lr]
  float mrun = -1e30f, lrun = 0.f;  // softmax state for q = lane&15 (x4 replicas)

  f16x8 kfA[2][4], kfB[2][4], vf[2][4];

  // prologue: K(0) -> kfA, K(1) -> kfB (clamped)
#pragma unroll
  for (int kc = 0; kc < 2; ++kc)
#pragma unroll
    for (int ni = 0; ni < 4; ++ni)
      kfA[kc][ni] = *(const f16x8*)(kbase + ni * 2048 + kc * 1024);
  {
    const char* k1 = kbase + (size_t)(nt > 1 ? 1 : 0) * 8192;
#pragma unroll
    for (int kc = 0; kc < 2; ++kc)
#pragma unroll
      for (int ni = 0; ni < 4; ++ni)
        kfB[kc][ni] = *(const f16x8*)(k1 + ni * 2048 + kc * 1024);
  }

  auto phase = [&](f16x8 (&kf)[2][4], int st) {
    // issue V(st) loads (consumed by PV below; cover = QK^T + softmax)
    const char* vt = vbase + (size_t)st * 8192;
#pragma unroll
    for (int kc = 0; kc < 2; ++kc)
#pragma unroll
      for (int nd = 0; nd < 4; ++nd)
        vf[kc][nd] = *(const f16x8*)(vt + nd * 2048 + kc * 1024);

    // S^T: sa[ni] = mfma(K, Q): lane holds S[s=st*64+ni*16+lk*4+r][q=lr]
    f32x4 sa[4] = {};
    __builtin_amdgcn_s_setprio(1);
#pragma unroll
    for (int kc = 0; kc < 2; ++kc)
#pragma unroll
      for (int ni = 0; ni < 4; ++ni)
        sa[ni] =
            __builtin_amdgcn_mfma_f32_16x16x32_f16(kf[kc][ni], qf[kc], sa[ni], 0, 0, 0);
    __builtin_amdgcn_s_setprio(0);

    // prefetch K(st+2) into the buffer just consumed (clamped; 2-phase cover)
    {
      const int stp = (st + 2 <= ntm1) ? st + 2 : ntm1;
      const char* kt = kbase + (size_t)stp * 8192;
#pragma unroll
      for (int kc = 0; kc < 2; ++kc)
#pragma unroll
        for (int ni = 0; ni < 4; ++ni)
          kf[kc][ni] = *(const f16x8*)(kt + ni * 2048 + kc * 1024);
    }

    if (st == ntm1) {  // diagonal tile: causal mask (s > q)
      const int s0 = st * 64;
#pragma unroll
      for (int ni = 0; ni < 4; ++ni)
#pragma unroll
        for (int r = 0; r < 4; ++r)
          if (s0 + ni * 16 + lk * 4 + r > t0 + w * 16 + lr) sa[ni][r] = -1e30f;
    }

    // lane-local row max, then reduce over the 4 replica lanes
    float mx;
    {
      float m0_ = fmaxf(fmaxf(sa[0][0], sa[0][1]), fmaxf(sa[0][2], sa[0][3]));
      float m1_ = fmaxf(fmaxf(sa[1][0], sa[1][1]), fmaxf(sa[1][2], sa[1][3]));
      float m2_ = fmaxf(fmaxf(sa[2][0], sa[2][1]), fmaxf(sa[2][2], sa[2][3]));
      float m3_ = fmaxf(fmaxf(sa[3][0], sa[3][1]), fmaxf(sa[3][2], sa[3][3]));
      mx = fmaxf(fmaxf(m0_, m1_), fmaxf(m2_, m3_));
      mx = fmaxf(mx, __shfl_xor(mx, 16));
      mx = fmaxf(mx, __shfl_xor(mx, 32));
    }

    // defer-max: rescale only when the wave sees max growth > 8 (log2 units)
    if (__any(mx > mrun + 8.0f)) {
      float mn = fmaxf(mrun, mx);
      float al = __builtin_amdgcn_exp2f(mrun - mn);
      mrun = mn;
      lrun *= al;
      float al4[4];
#pragma unroll
      for (int r = 0; r < 4; ++r) al4[r] = __shfl(al, lk * 4 + r);
#pragma unroll
      for (int nd = 0; nd < 4; ++nd)
#pragma unroll
        for (int r = 0; r < 4; ++r) of[nd][r] *= al4[r];
    }

    // P = exp2(sa - mrun); pack PV A-fragments: pa[kc] slot 4*hi+m holds
    // P[q=lr][s = 32kc + 16hi + 4lk + m]  (hi = ni&1, m = r)
    f16x8 pa[2];
    float rs;
    {
      float rn[4];
#pragma unroll
      for (int ni = 0; ni < 4; ++ni) {
        float p0 = __builtin_amdgcn_exp2f(sa[ni][0] - mrun);
        float p1 = __builtin_amdgcn_exp2f(sa[ni][1] - mrun);
        float p2 = __builtin_amdgcn_exp2f(sa[ni][2] - mrun);
        float p3 = __builtin_amdgcn_exp2f(sa[ni][3] - mrun);
        rn[ni] = (p0 + p1) + (p2 + p3);
        pa[ni >> 1][(ni & 1) * 4 + 0] = (_Float16)p0;
        pa[ni >> 1][(ni & 1) * 4 + 1] = (_Float16)p1;
        pa[ni >> 1][(ni & 1) * 4 + 2] = (_Float16)p2;
        pa[ni >> 1][(ni & 1) * 4 + 3] = (_Float16)p3;
      }
      rs = (rn[0] + rn[1]) + (rn[2] + rn[3]);
      rs += __shfl_xor(rs, 16);
      rs += __shfl_xor(rs, 32);
    }
    lrun += rs;

    // O += P V (B-fragment = vf, slot j = hi*4+m matches pa by construction)
    __builtin_amdgcn_s_setprio(1);
#pragma unroll
    for (int kc = 0; kc < 2; ++kc)
#pragma unroll
      for (int nd = 0; nd < 4; ++nd)
        of[nd] =
            __builtin_amdgcn_mfma_f32_16x16x32_f16(pa[kc], vf[kc][nd], of[nd], 0, 0, 0);
    __builtin_amdgcn_s_setprio(0);
  };

  int st = 0;
  while (st + 1 < nt) {
    phase(kfA, st);
    phase(kfB, st + 1);
    st += 2;
  }
  if (st < nt) phase(kfA, st);

  // epilogue: need lrun for q = lk*4+r (owner lane lr = q)
  float linv[4];
#pragma unroll
  for (int r = 0; r < 4; ++r) linv[r] = __shfl(lrun, lk * 4 + r);
  const int b = bh / TH, h = bh - b * TH;
#pragma unroll
  for (int nd = 0; nd < 4; ++nd) {
#pragma unroll
    for (int r = 0; r < 4; ++r) {
      int tg = t0 + w * 16 + lk * 4 + r;
      int d = nd * 16 + lr;
      ob[(size_t)(b * TT + tg) * TE + h * TD + d] = (_Float16)(of[nd][r] / linv[r]);
    }
  }
}

// ---------------------------------------------------------------------------
extern "C" void kernel_launch(void* const* d_in, const int* in_sizes, int n_in,
                              void* d_out, int out_size, void* d_ws, size_t ws_size,
                              hipStream_t stream) {
  const float* x    = (const float*)d_in[0];
  const float* wqkv = (const float*)d_in[1];
  const float* bqkv = (const float*)d_in[2];
  const float* wfin = (const float*)d_in[3];
  float* out = (float*)d_out;

  _Float16* xh  = (_Float16*)d_ws;          // [4096][768] row-major
  _Float16* wqh = xh + (size_t)TM * TK;     // fragment-native Wf
  _Float16* wfh = wqh + (size_t)NQKV * TK;  // fragment-native Wf
  _Float16* qb  = wfh + (size_t)TE * TE;    // [B,H,T,D] (pre-scaled)
  _Float16* kb  = qb + (size_t)TM * TE;     // K' fragment-native
  _Float16* vtb = kb + (size_t)TM * TE;     // V' fragment-native
  _Float16* ob  = vtb + (size_t)TM * TE;    // [4096][768] attn output

  cvt3<<<5376, 256, 0, stream>>>(x, wqkv, wfin, xh, wqh, wfh);
  gemm_nt<0, NQKV / 128><<<(NQKV / 128) * (TM / 128), 512, 0, stream>>>(
      xh, wqh, bqkv, qb, kb, vtb, nullptr);
  attn_kernel<<<dim3(TT / 64 * TB * TH), 256, 0, stream>>>(qb, kb, vtb, ob);
  gemm_nt<1, TE / 128><<<(TE / 128) * (TM / 128), 512, 0, stream>>>(
      ob, wfh, nullptr, nullptr, nullptr, nullptr, out);
}

// Round 15
// 82.180 us; speedup vs baseline: 1.2488x; 1.0684x over previous
//
#include <hip/hip_runtime.h>
#include <cstdint>

typedef _Float16 f16x8 __attribute__((ext_vector_type(8)));
typedef _Float16 f16x4 __attribute__((ext_vector_type(4)));
typedef float    f32x4 __attribute__((ext_vector_type(4)));

static constexpr int TB = 2;
static constexpr int TT = 2048;
static constexpr int TE = 768;
static constexpr int TH = 12;
static constexpr int TD = 64;
static constexpr int TM = TB * TT;      // 4096 rows (B*T)
static constexpr int TK = TE;           // 768 (K for both GEMMs)
static constexpr int NQKV = 3 * TE;     // 2304

#define SCALE_LOG2E 0.18033688011112042f  /* (1/sqrt(64)) * log2(e) */

// async global->LDS, 16B per lane. LDS dest is wave-uniform base + lane*16.
__device__ __forceinline__ void gload16(const void* g, void* lds) {
  __builtin_amdgcn_global_load_lds(
      (__attribute__((address_space(1))) void*)(uintptr_t)g,
      (__attribute__((address_space(3))) void*)(uint32_t)(uintptr_t)lds, 16, 0, 0);
}

// ---------------------------------------------------------------------------
// f32 -> f16 convert. x -> row-major f16. w_qkv / w_final -> FRAGMENT-NATIVE
// Wf layout: f16 idx(n,k) = ((n>>4)*24 + (k>>5))*512 + ((k>>3)&3)*128
//                           + (n&15)*8 + (k&7)
// ---------------------------------------------------------------------------
__global__ void cvt3(const float* __restrict__ x, const float* __restrict__ wq,
                     const float* __restrict__ wf, _Float16* __restrict__ xh,
                     _Float16* __restrict__ wqh, _Float16* __restrict__ wfh) {
  const int NX = TM * TK / 4, NW = NQKV * TK / 4;
  int i = blockIdx.x * 256 + threadIdx.x;
  if (i < NX) {
    float4 v = ((const float4*)x)[i];
    f16x4 o = {(_Float16)v.x, (_Float16)v.y, (_Float16)v.z, (_Float16)v.w};
    *(f16x4*)&xh[(size_t)i * 4] = o;
  } else {
    const float4* src; _Float16* dst; int j;
    if (i < NX + NW) { src = (const float4*)wq; dst = wqh; j = i - NX; }
    else             { src = (const float4*)wf; dst = wfh; j = i - NX - NW; }
    float4 v = src[j];
    f16x4 o = {(_Float16)v.x, (_Float16)v.y, (_Float16)v.z, (_Float16)v.w};
    const int flat = j * 4;
    const int n = flat / TK, k = flat % TK;
    const size_t idx = ((size_t)(n >> 4) * 24 + (k >> 5)) * 512 +
                       ((k >> 3) & 3) * 128 + (n & 15) * 8 + (k & 7);
    *(f16x4*)&dst[idx] = o;
  }
}

// ---------------------------------------------------------------------------
// NT GEMM: C[M,N] = A[M,K] * Wf[N,K]^T (+bias). Tile MT x 128, BK=64,
// 4 waves, wave = 64x32 out. TRIPLE-BUFFERED, ONE barrier per K-step,
// prefetch distance 2. RACE-FIXED schedule (R14 post-mortem): per step ks
//   wait own vmcnt (certify step ks's chunks) -> s_barrier (publish; also
//   separates from all waves' compute(ks-1)) -> issue B(ks+2)->regs +
//   A(ks+2)->LDS into buffer (ks+2)%3 -> compute(ks) from As[ks%3]/b(ks%3).
// stage(ks+2) writes (ks+2)%3 == (ks-1)%3, whose readers (compute(ks-1))
// all finished BEFORE this step's barrier -> WAR-safe.
// vmcnt: 6 loads/step; at wait point 12 outstanding (ks, ks+1) -> vmcnt(6)
// drains the 6 oldest (= step ks's); last step vmcnt(0).
// B register buffers NAMED b0/b1/b2 (no runtime indexing), period-3 loop.
// EPI=0: qkv epilogue (Q pre-scaled; K',V' fragment-native). EPI=1: f32 out.
// ---------------------------------------------------------------------------
template <int EPI, int MT, int NXT, int MPX>
__global__ __launch_bounds__(MT * 4)
void gemm_nt(const _Float16* __restrict__ A, const _Float16* __restrict__ Bw,
             const float* __restrict__ bias,
             _Float16* __restrict__ qb, _Float16* __restrict__ kb,
             _Float16* __restrict__ vtb, float* __restrict__ outp) {
  __shared__ _Float16 As[3][MT * 64];
  const int tid = threadIdx.x;
  const int w = tid >> 6, lane = tid & 63;
  const int lr = lane & 15, lk = lane >> 4;

  const int id = blockIdx.x;
  const int xcd = id & 7, j = id >> 3;
  const int m0 = (xcd * MPX + j / NXT) * MT;
  const int n0 = (j % NXT) * 128;
  const int wr = (MT == 128) ? (w >> 2) : 0;
  const int wc = (MT == 128) ? (w & 3) : w;

  f32x4 acc[4][2] = {};
  const char* Ab = (const char*)(A + (size_t)m0 * TK);
  const char* WB = (const char*)Bw;
  const int nb = (n0 >> 4) + wc * 2;
  constexpr int NS = TK / 64;  // 12 K-steps

  auto loadB = [&](int ks, f16x8 (&bf)[2][2]) {
#pragma unroll
    for (int ni = 0; ni < 2; ++ni)
#pragma unroll
      for (int kc = 0; kc < 2; ++kc)
        bf[ni][kc] = *(const f16x8*)(WB +
                                     ((size_t)(nb + ni) * 24 + ks * 2 + kc) * 1024 +
                                     lane * 16);
  };
  auto stageA = [&](int ks, _Float16* L) {
#pragma unroll
    for (int c = 0; c < 2; ++c) {
      int g = w * 2 + c;  // chunk of the MT*128B A tile
      int o = g * 1024 + lane * 16;
      int row = o >> 7, ch = (o >> 4) & 7;
      gload16(Ab + (size_t)row * (TK * 2) + ks * 128 + ((ch ^ (row & 7)) << 4),
              (char*)L + g * 1024);
    }
  };
  auto step = [&](f16x8 (&bc)[2][2], f16x8 (&bn)[2][2], _Float16* Lc,
                  _Float16* Ln, int ks) {
    if (ks < NS - 1) {
      asm volatile("s_waitcnt vmcnt(6)" ::: "memory");  // step ks's 6 landed
    } else {
      asm volatile("s_waitcnt vmcnt(0)" ::: "memory");
    }
    __builtin_amdgcn_s_barrier();  // publish ks; fence off compute(ks-1)
    if (ks < NS - 2) {
      loadB(ks + 2, bn);   // 4 reg loads (consumed at step ks+2)
      stageA(ks + 2, Ln);  // 2 gload16 -> As[(ks+2)%3] (WAR-safe, see above)
    }
#pragma unroll
    for (int kc = 0; kc < 2; ++kc) {
      f16x8 af[4];
#pragma unroll
      for (int mi = 0; mi < 4; ++mi) {
        int row = wr * 64 + mi * 16 + lr;
        af[mi] = *(const f16x8*)&Lc[row * 64 + (((kc * 4 + lk) ^ (row & 7)) << 3)];
      }
#pragma unroll
      for (int mi = 0; mi < 4; ++mi)
#pragma unroll
        for (int ni = 0; ni < 2; ++ni)
          acc[mi][ni] = __builtin_amdgcn_mfma_f32_16x16x32_f16(af[mi], bc[ni][kc],
                                                               acc[mi][ni], 0, 0, 0);
    }
  };

  f16x8 b0[2][2], b1[2][2], b2[2][2];
  loadB(0, b0);
  stageA(0, As[0]);
  loadB(1, b1);
  stageA(1, As[1]);
  for (int kss = 0; kss < NS; kss += 3) {  // NS=12: buffer indices fold
    step(b0, b2, As[0], As[2], kss);
    step(b1, b0, As[1], As[0], kss + 1);
    step(b2, b1, As[2], As[1], kss + 2);
  }

  // epilogue: C layout col = lane&15 (N), row = (lane>>4)*4 + r
#pragma unroll
  for (int mi = 0; mi < 4; ++mi) {
#pragma unroll
    for (int ni = 0; ni < 2; ++ni) {
      const int col = n0 + wc * 32 + ni * 16 + lr;
#pragma unroll
      for (int r = 0; r < 4; ++r) {
        const int row = m0 + wr * 64 + mi * 16 + lk * 4 + r;
        float v = acc[mi][ni][r];
        if (EPI == 0) {
          v += bias[col];
          const int which = (col >= 2 * TE) ? 2 : (col >= TE ? 1 : 0);
          const int e = col - which * TE;
          const int h = e >> 6, d = e & 63;
          const int b = row >> 11, t = row & (TT - 1);
          const size_t hb = (size_t)(b * TH + h);
          if (which == 0) {
            qb[(hb * TT + t) * TD + d] = (_Float16)(v * SCALE_LOG2E);
          } else if (which == 1) {
            // K' fragment-native
            kb[((((hb * 128 + (t >> 4)) * 8 + (d >> 3)) * 16 + (t & 15)) * 8) +
               (d & 7)] = (_Float16)v;
          } else {
            // V' fragment-native
            const int kc = (t >> 5) & 1, hi = (t >> 4) & 1;
            const int lkv = (t >> 2) & 3, m = t & 3;
            vtb[((((((hb * 32 + (t >> 6)) * 4 + (d >> 4)) * 2 + kc) * 4 + lkv) *
                      16 +
                  (d & 15)) *
                 8) +
                (hi * 4 + m)] = (_Float16)v;
          }
        } else {
          outp[(size_t)row * TE + col] = v;
        }
      }
    }
  }
}

// ---------------------------------------------------------------------------
// Causal flash attention, BARRIER-FREE, NO LDS (R7/R13 config — best
// measured). Grid 768 = 24 heads x 32 q-tiles (bh = id%24, qt = 31 - id/24).
// 4 independent waves/block; wave w owns 16 q-rows. K,V fragment-native
// global -> contiguous 1KB wave loads to VGPR; kfA/kfB register dbuf, K
// prefetched 2 tiles ahead, V issued at phase start. SWAPPED QK^T
// (mfma(K,Q)): lane-local softmax; P never leaves registers. T13 defer-max.
// ---------------------------------------------------------------------------
__global__ __launch_bounds__(256)
void attn_kernel(const _Float16* __restrict__ qbuf, const _Float16* __restrict__ kbuf,
                 const _Float16* __restrict__ vtbuf, _Float16* __restrict__ ob) {
  const int tid = threadIdx.x, w = tid >> 6, lane = tid & 63;
  const int lr = lane & 15, lk = lane >> 4;

  const int id = blockIdx.x;        // 0..767
  const int bh = id % 24;
  const int qt = 31 - id / 24;      // heavy first, balanced per CU
  const int t0 = qt * 64;
  const int nt = qt + 1, ntm1 = qt;

  const _Float16* q = qbuf + (size_t)bh * (TT * TD);  // [T][64], pre-scaled
  const char* kbase =
      (const char*)(kbuf + (size_t)bh * (TT * TD)) + lk * 256 + lr * 16;
  const char* vbase =
      (const char*)(vtbuf + (size_t)bh * (TT * TD)) + lk * 256 + lr * 16;

  f16x8 qf[2];  // B-operand: Q[q=t0+w*16+lr][kc*32+lk*8 ..]
#pragma unroll
  for (int kc = 0; kc < 2; ++kc)
    qf[kc] = *(const f16x8*)&q[(size_t)(t0 + w * 16 + lr) * TD + kc * 32 + lk * 8];

  f32x4 of[4] = {};                 // O[q=lk*4+r][d=nd*16+lr]
  float mrun = -1e30f, lrun = 0.f;  // softmax state for q = lane&15 (x4 replicas)

  f16x8 kfA[2][4], kfB[2][4], vf[2][4];

  // prologue: K(0) -> kfA, K(1) -> kfB (clamped)
#pragma unroll
  for (int kc = 0; kc < 2; ++kc)
#pragma unroll
    for (int ni = 0; ni < 4; ++ni)
      kfA[kc][ni] = *(const f16x8*)(kbase + ni * 2048 + kc * 1024);
  {
    const char* k1 = kbase + (size_t)(nt > 1 ? 1 : 0) * 8192;
#pragma unroll
    for (int kc = 0; kc < 2; ++kc)
#pragma unroll
      for (int ni = 0; ni < 4; ++ni)
        kfB[kc][ni] = *(const f16x8*)(k1 + ni * 2048 + kc * 1024);
  }

  auto phase = [&](f16x8 (&kf)[2][4], int st) {
    // issue V(st) loads (consumed by PV below; cover = QK^T + softmax)
    const char* vt = vbase + (size_t)st * 8192;
#pragma unroll
    for (int kc = 0; kc < 2; ++kc)
#pragma unroll
      for (int nd = 0; nd < 4; ++nd)
        vf[kc][nd] = *(const f16x8*)(vt + nd * 2048 + kc * 1024);

    // S^T: sa[ni] = mfma(K, Q): lane holds S[s=st*64+ni*16+lk*4+r][q=lr]
    f32x4 sa[4] = {};
    __builtin_amdgcn_s_setprio(1);
#pragma unroll
    for (int kc = 0; kc < 2; ++kc)
#pragma unroll
      for (int ni = 0; ni < 4; ++ni)
        sa[ni] =
            __builtin_amdgcn_mfma_f32_16x16x32_f16(kf[kc][ni], qf[kc], sa[ni], 0, 0, 0);
    __builtin_amdgcn_s_setprio(0);

    // prefetch K(st+2) into the buffer just consumed (clamped; 2-phase cover)
    {
      const int stp = (st + 2 <= ntm1) ? st + 2 : ntm1;
      const char* kt = kbase + (size_t)stp * 8192;
#pragma unroll
      for (int kc = 0; kc < 2; ++kc)
#pragma unroll
        for (int ni = 0; ni < 4; ++ni)
          kf[kc][ni] = *(const f16x8*)(kt + ni * 2048 + kc * 1024);
    }

    if (st == ntm1) {  // diagonal tile: causal mask (s > q)
      const int s0 = st * 64;
#pragma unroll
      for (int ni = 0; ni < 4; ++ni)
#pragma unroll
        for (int r = 0; r < 4; ++r)
          if (s0 + ni * 16 + lk * 4 + r > t0 + w * 16 + lr) sa[ni][r] = -1e30f;
    }

    // lane-local row max, then reduce over the 4 replica lanes
    float mx;
    {
      float m0_ = fmaxf(fmaxf(sa[0][0], sa[0][1]), fmaxf(sa[0][2], sa[0][3]));
      float m1_ = fmaxf(fmaxf(sa[1][0], sa[1][1]), fmaxf(sa[1][2], sa[1][3]));
      float m2_ = fmaxf(fmaxf(sa[2][0], sa[2][1]), fmaxf(sa[2][2], sa[2][3]));
      float m3_ = fmaxf(fmaxf(sa[3][0], sa[3][1]), fmaxf(sa[3][2], sa[3][3]));
      mx = fmaxf(fmaxf(m0_, m1_), fmaxf(m2_, m3_));
      mx = fmaxf(mx, __shfl_xor(mx, 16));
      mx = fmaxf(mx, __shfl_xor(mx, 32));
    }

    // defer-max: rescale only when the wave sees max growth > 8 (log2 units)
    if (__any(mx > mrun + 8.0f)) {
      float mn = fmaxf(mrun, mx);
      float al = __builtin_amdgcn_exp2f(mrun - mn);
      mrun = mn;
      lrun *= al;
      float al4[4];
#pragma unroll
      for (int r = 0; r < 4; ++r) al4[r] = __shfl(al, lk * 4 + r);
#pragma unroll
      for (int nd = 0; nd < 4; ++nd)
#pragma unroll
        for (int r = 0; r < 4; ++r) of[nd][r] *= al4[r];
    }

    // P = exp2(sa - mrun); pack PV A-fragments: pa[kc] slot 4*hi+m holds
    // P[q=lr][s = 32kc + 16hi + 4lk + m]  (hi = ni&1, m = r)
    f16x8 pa[2];
    float rs;
    {
      float rn[4];
#pragma unroll
      for (int ni = 0; ni < 4; ++ni) {
        float p0 = __builtin_amdgcn_exp2f(sa[ni][0] - mrun);
        float p1 = __builtin_amdgcn_exp2f(sa[ni][1] - mrun);
        float p2 = __builtin_amdgcn_exp2f(sa[ni][2] - mrun);
        float p3 = __builtin_amdgcn_exp2f(sa[ni][3] - mrun);
        rn[ni] = (p0 + p1) + (p2 + p3);
        pa[ni >> 1][(ni & 1) * 4 + 0] = (_Float16)p0;
        pa[ni >> 1][(ni & 1) * 4 + 1] = (_Float16)p1;
        pa[ni >> 1][(ni & 1) * 4 + 2] = (_Float16)p2;
        pa[ni >> 1][(ni & 1) * 4 + 3] = (_Float16)p3;
      }
      rs = (rn[0] + rn[1]) + (rn[2] + rn[3]);
      rs += __shfl_xor(rs, 16);
      rs += __shfl_xor(rs, 32);
    }
    lrun += rs;

    // O += P V (B-fragment = vf, slot j = hi*4+m matches pa by construction)
    __builtin_amdgcn_s_setprio(1);
#pragma unroll
    for (int kc = 0; kc < 2; ++kc)
#pragma unroll
      for (int nd = 0; nd < 4; ++nd)
        of[nd] =
            __builtin_amdgcn_mfma_f32_16x16x32_f16(pa[kc], vf[kc][nd], of[nd], 0, 0, 0);
    __builtin_amdgcn_s_setprio(0);
  };

  int st = 0;
  while (st + 1 < nt) {
    phase(kfA, st);
    phase(kfB, st + 1);
    st += 2;
  }
  if (st < nt) phase(kfA, st);

  // epilogue: need lrun for q = lk*4+r (owner lane lr = q)
  float linv[4];
#pragma unroll
  for (int r = 0; r < 4; ++r) linv[r] = __shfl(lrun, lk * 4 + r);
  const int b = bh / TH, h = bh - b * TH;
#pragma unroll
  for (int nd = 0; nd < 4; ++nd) {
#pragma unroll
    for (int r = 0; r < 4; ++r) {
      int tg = t0 + w * 16 + lk * 4 + r;
      int d = nd * 16 + lr;
      ob[(size_t)(b * TT + tg) * TE + h * TD + d] = (_Float16)(of[nd][r] / linv[r]);
    }
  }
}

// ---------------------------------------------------------------------------
extern "C" void kernel_launch(void* const* d_in, const int* in_sizes, int n_in,
                              void* d_out, int out_size, void* d_ws, size_t ws_size,
                              hipStream_t stream) {
  const float* x    = (const float*)d_in[0];
  const float* wqkv = (const float*)d_in[1];
  const float* bqkv = (const float*)d_in[2];
  const float* wfin = (const float*)d_in[3];
  float* out = (float*)d_out;

  _Float16* xh  = (_Float16*)d_ws;          // [4096][768] row-major
  _Float16* wqh = xh + (size_t)TM * TK;     // fragment-native Wf
  _Float16* wfh = wqh + (size_t)NQKV * TK;  // fragment-native Wf
  _Float16* qb  = wfh + (size_t)TE * TE;    // [B,H,T,D] (pre-scaled)
  _Float16* kb  = qb + (size_t)TM * TE;     // K' fragment-native
  _Float16* vtb = kb + (size_t)TM * TE;     // V' fragment-native
  _Float16* ob  = vtb + (size_t)TM * TE;    // [4096][768] attn output

  cvt3<<<5376, 256, 0, stream>>>(x, wqkv, wfin, xh, wqh, wfh);
  gemm_nt<0, 64, NQKV / 128, 8><<<8 * 8 * (NQKV / 128), 256, 0, stream>>>(
      xh, wqh, bqkv, qb, kb, vtb, nullptr);
  attn_kernel<<<dim3(TT / 64 * TB * TH), 256, 0, stream>>>(qb, kb, vtb, ob);
  gemm_nt<1, 64, TE / 128, 8><<<8 * 8 * (TE / 128), 256, 0, stream>>>(
      ob, wfh, nullptr, nullptr, nullptr, nullptr, out);
}